// Round 8
// baseline (160.001 us; speedup 1.0000x reference)
//
#include <hip/hip_runtime.h>

typedef __bf16 bf16;
typedef __attribute__((ext_vector_type(8))) __bf16 bf16x8;
typedef __attribute__((ext_vector_type(4))) __bf16 bf16x4;
typedef __attribute__((ext_vector_type(4))) float floatx4;

#define MFMA16(a, b, c) __builtin_amdgcn_mfma_f32_16x16x32_bf16((a), (b), (c), 0, 0, 0)

// ---------------------------------------------------------------------------
// Kernel 0: W [1024][64] fp32 x3 -> wTf, FRAGMENT-MAJOR bf16:
//   wTf[(((mt*32 + kc)*4 + q)*16 + l)*8 + j] = A[m = mt*16+l][k = kc*32+q*8+j]
//   where A[m][c] = W_{m/64}[c][m%64].
// ---------------------------------------------------------------------------
__global__ void prep_w(const float* __restrict__ Wq, const float* __restrict__ Wk,
                       const float* __restrict__ Wv, bf16* __restrict__ wTf) {
    int tid = blockIdx.x * 256 + threadIdx.x;   // [0, 196608)
    int j = tid & 7;
    int l = (tid >> 3) & 15;
    int q = (tid >> 7) & 3;
    int kc = (tid >> 9) & 31;
    int mt = tid >> 14;                          // 0..11
    int mat = mt >> 2;
    int h = ((mt & 3) << 4) + l;
    int c = kc * 32 + q * 8 + j;
    const float* W = (mat == 0) ? Wq : (mat == 1) ? Wk : Wv;
    wTf[tid] = (bf16)W[c * 64 + h];
}

// ---------------------------------------------------------------------------
// Kernel 1: QKV projection. Block = 256 thr (4 waves) = ONE 32-row t-tile.
// Each wave: m-group w (3 m-tiles) x BOTH 16-row t-halves -> A-frags read once
// per 32 rows (L2 wTf traffic halves vs 16-row blocks: 402 -> 201 MB).
// Stage: 64 KB LDS x-tile, bf16, XOR-granule swizzle (slot = g ^ (row&7)) so
// both staging stores and compute ds_read_b128 are bank-uniform.
// Compute: depth-3 rotating A prefetch (~240cy >= L2 latency).
// Grid 512 = 2 blocks/CU (64 KB LDS).
// ---------------------------------------------------------------------------
__global__ __launch_bounds__(256, 4) void proj_qkv(const float* __restrict__ x,
                                                   const bf16* __restrict__ wTf,
                                                   bf16* __restrict__ q,
                                                   bf16* __restrict__ k,
                                                   bf16* __restrict__ vT) {
    __shared__ bf16 xs[32 * 1024];   // 64 KB exactly (R3 proved this compiles)

    const int tid = threadIdx.x;
    const int lane = tid & 63;
    const int w = tid >> 6;          // wave 0..3 = m-group
    const int l15 = lane & 15;
    const int quad = lane >> 4;
    const int T0 = blockIdx.x * 32;

    // ---- stage: thread -> row r = tid>>3, granule set cm = tid&7.
    // granule = 8 bf16 (16B LDS / 32B global). slot = granule ^ (r&7).
    {
        const int r = tid >> 3;
        const int cm = tid & 7;
        const float* g = x + (size_t)(T0 + r) * 1024 + cm * 8;
        bf16* ld = xs + r * 1024;
        const int sw = r & 7;
        #pragma unroll
        for (int jb = 0; jb < 4; jb++) {
            floatx4 f[8];
            #pragma unroll
            for (int jj = 0; jj < 4; jj++) {
                f[2*jj]   = __builtin_nontemporal_load((const floatx4*)(g + (jb*4+jj) * 64));
                f[2*jj+1] = __builtin_nontemporal_load((const floatx4*)(g + (jb*4+jj) * 64 + 4));
            }
            #pragma unroll
            for (int jj = 0; jj < 4; jj++) {
                int gg = cm + (jb*4+jj) * 8;
                bf16x8 pk;
                pk[0] = (bf16)f[2*jj][0]; pk[1] = (bf16)f[2*jj][1];
                pk[2] = (bf16)f[2*jj][2]; pk[3] = (bf16)f[2*jj][3];
                pk[4] = (bf16)f[2*jj+1][0]; pk[5] = (bf16)f[2*jj+1][1];
                pk[6] = (bf16)f[2*jj+1][2]; pk[7] = (bf16)f[2*jj+1][3];
                *(bf16x8*)(ld + ((gg ^ sw) << 3)) = pk;
            }
        }
    }
    __syncthreads();

    // ---- compute: depth-3 rotating A prefetch, 2 t-tiles per wave
    floatx4 acc[3][2] = {};
    const bf16* aw0 = wTf + (size_t)(w * 3 + 0) * 16384 + lane * 8;
    const bf16* aw1 = wTf + (size_t)(w * 3 + 1) * 16384 + lane * 8;
    const bf16* aw2 = wTf + (size_t)(w * 3 + 2) * 16384 + lane * 8;
    const bf16* xr0 = xs + l15 * 1024;          // t-rows 0..15
    const bf16* xr1 = xs + (16 + l15) * 1024;   // t-rows 16..31 (same swizzle: (16+l15)&7 == l15&7)
    const int swz = l15 & 7;

    bf16x8 A0[3], A1[3], A2[3];
    #pragma unroll
    for (int i = 0; i < 3; i++) {
        A0[i] = *(const bf16x8*)(aw0 + i * 512);
        A1[i] = *(const bf16x8*)(aw1 + i * 512);
        A2[i] = *(const bf16x8*)(aw2 + i * 512);
    }

    #pragma unroll
    for (int kc = 0; kc < 32; kc++) {
        const int idx = kc % 3;                  // constant after full unroll
        bf16x8 a0 = A0[idx], a1 = A1[idx], a2 = A2[idx];
        if (kc < 29) {                           // prefetch kc+3 into freed slot
            A0[idx] = *(const bf16x8*)(aw0 + (kc + 3) * 512);
            A1[idx] = *(const bf16x8*)(aw1 + (kc + 3) * 512);
            A2[idx] = *(const bf16x8*)(aw2 + (kc + 3) * 512);
        }
        const int sl = (((kc * 4 + quad) ^ swz) << 3);
        bf16x8 b0 = *(const bf16x8*)(xr0 + sl);
        bf16x8 b1 = *(const bf16x8*)(xr1 + sl);
        acc[0][0] = MFMA16(a0, b0, acc[0][0]);
        acc[0][1] = MFMA16(a0, b1, acc[0][1]);
        acc[1][0] = MFMA16(a1, b0, acc[1][0]);
        acc[1][1] = MFMA16(a1, b1, acc[1][1]);
        acc[2][0] = MFMA16(a2, b0, acc[2][0]);
        acc[2][1] = MFMA16(a2, b1, acc[2][1]);
    }

    // Epilogue. C-layout: (i,tt) -> out-row m = (w*3+i)*16 + quad*4 + r
    // (mat = m/64, h = m%64), out-col t = T0 + tt*16 + l15. q gets 1/8 folded.
    #pragma unroll
    for (int i = 0; i < 3; i++) {
        int mtile = w * 3 + i;
        int mat = mtile >> 2;                          // wave-uniform
        int hbase = ((mtile & 3) << 4) + (quad << 2);
        float sc = (mat == 0) ? 0.125f : 1.0f;
        #pragma unroll
        for (int tt = 0; tt < 2; tt++) {
            int t = T0 + tt * 16 + l15;
            bf16x4 pk;
            pk[0] = (bf16)(acc[i][tt][0] * sc);
            pk[1] = (bf16)(acc[i][tt][1] * sc);
            pk[2] = (bf16)(acc[i][tt][2] * sc);
            pk[3] = (bf16)(acc[i][tt][3] * sc);
            if (mat == 0) {
                *(bf16x4*)(q + (size_t)t * 64 + hbase) = pk;
            } else if (mat == 1) {
                *(bf16x4*)(k + (size_t)t * 64 + hbase) = pk;
            } else {
                int b = t >> 11, tts = t & 2047;
                #pragma unroll
                for (int r = 0; r < 4; r++)
                    vT[(size_t)(b * 64 + hbase + r) * 2048 + tts] = pk[r];
            }
        }
    }
}

// ---------------------------------------------------------------------------
// Kernel 2: causal flash attention, S^T formulation, 1024-thr blocks:
// 16 waves split the uniform (p, 127-p) Q-tile pair's KV slots 16 ways
// (~2 slots/wave serial path, half of R7). K depth-1 register pipeline.
// 16-partial merge is HIERARCHICAL (4 rounds tile A, 3+1 rounds tile B; the
// asymmetric final leaves A in wave 0, B in wave 1 -> parallel output writes)
// over one 8-slot LDS buffer unioned with ps. Direct identifiers everywhere
// (R6: runtime pointers into register arrays force scratch spills).
// ---------------------------------------------------------------------------
#define KP2 72
#define OH2 68

__global__ __launch_bounds__(1024, 4) void flash(const bf16* __restrict__ q,
                                                 const bf16* __restrict__ k,
                                                 const bf16* __restrict__ vT,
                                                 float* __restrict__ out) {
    __shared__ char smem[16 * 16 * KP2 * 2];   // 36864 B: ps (loop) / Ob (merge)
    __shared__ float Mb[8][16], Lb[8][16];
    bf16* psall = (bf16*)smem;
    float* Ob = (float*)smem;                  // [8][16][OH2]

    const int b = blockIdx.x & 7;              // batch -> XCD affinity
    const int p = blockIdx.x >> 3;             // 0..63
    const int t0A = p * 16;
    const int t0B = (127 - p) * 16;
    const int nttA = (p >> 2) + 1;
    const int nttB = ((127 - p) >> 2) + 1;
    const int L = nttA + nttB;                 // 32..34 for all blocks

    const int tid = threadIdx.x;
    const int w = tid >> 6;                    // wave 0..15
    const int lane = tid & 63;
    const int l15 = lane & 15;
    const int quad = lane >> 4;

    const int s0 = (L * w) >> 4;
    const int s1 = (L * (w + 1)) >> 4;         // 2-3 slots per wave

    const bf16* kbase = k + (size_t)(b * 2048 + l15) * 64 + quad * 8;   // + jt*4096 + mt*1024
    const bf16* vbase = vT + (size_t)(b * 64 + l15) * 2048 + quad * 8;  // + mt*32768 + jt*64 + kc*32
    bf16* psw = psall + w * 16 * KP2;

    const bf16* qpA = q + (size_t)(b * 2048 + t0A + l15) * 64 + quad * 8;
    const bf16* qpB = q + (size_t)(b * 2048 + t0B + l15) * 64 + quad * 8;
    bf16x8 qfA0 = *(const bf16x8*)qpA;
    bf16x8 qfA1 = *(const bf16x8*)(qpA + 32);
    bf16x8 qfB0 = *(const bf16x8*)qpB;
    bf16x8 qfB1 = *(const bf16x8*)(qpB + 32);

    floatx4 oA[4] = {}, oB[4] = {};
    float miA = -1e30f, liA = 0.f, miB = -1e30f, liB = 0.f;

    // preload K for slot s0
    bf16x8 kf[8];
    {
        int j0 = (s0 < nttA) ? s0 : (s0 - nttA);
        const bf16* kp = kbase + (size_t)j0 * 4096;
        #pragma unroll
        for (int mt = 0; mt < 4; mt++) {
            kf[2 * mt]     = *(const bf16x8*)(kp + mt * 1024);
            kf[2 * mt + 1] = *(const bf16x8*)(kp + mt * 1024 + 32);
        }
    }

#define KV_STEP(sv, jtv, isdiag, t0v, qf0v, qf1v, mi_, li_, o_)                      \
    {                                                                                 \
        floatx4 stt[4];                                                               \
        _Pragma("unroll") for (int mt = 0; mt < 4; mt++) {                            \
            floatx4 z = {};                                                           \
            z = MFMA16(kf[2 * mt], qf0v, z);                                          \
            z = MFMA16(kf[2 * mt + 1], qf1v, z);                                      \
            stt[mt] = z;                                                              \
        }                                                                             \
        {   /* kf consumed -> prefetch next slot's K under softmax+PV */              \
            int snx = (sv) + 1;                                                       \
            if (snx < s1) {                                                           \
                int jn = (snx < nttA) ? snx : (snx - nttA);                           \
                const bf16* kpn = kbase + (size_t)jn * 4096;                          \
                _Pragma("unroll") for (int mt = 0; mt < 4; mt++) {                    \
                    kf[2 * mt]     = *(const bf16x8*)(kpn + mt * 1024);               \
                    kf[2 * mt + 1] = *(const bf16x8*)(kpn + mt * 1024 + 32);          \
                }                                                                     \
            }                                                                         \
        }                                                                             \
        if (isdiag) {                                                                 \
            _Pragma("unroll") for (int mt = 0; mt < 4; mt++)                          \
                _Pragma("unroll") for (int r = 0; r < 4; r++) {                       \
                    int kv = (jtv) * 64 + mt * 16 + quad * 4 + r;                     \
                    if (kv > (t0v) + l15) stt[mt][r] = -1e30f;                        \
                }                                                                     \
        }                                                                             \
        float mx = fmaxf(fmaxf(fmaxf(stt[0][0], stt[0][1]), fmaxf(stt[0][2], stt[0][3])),  \
                         fmaxf(fmaxf(stt[1][0], stt[1][1]), fmaxf(stt[1][2], stt[1][3]))); \
        mx = fmaxf(mx, fmaxf(fmaxf(fmaxf(stt[2][0], stt[2][1]), fmaxf(stt[2][2], stt[2][3])),  \
                             fmaxf(fmaxf(stt[3][0], stt[3][1]), fmaxf(stt[3][2], stt[3][3])))); \
        mx = fmaxf(mx, __shfl_xor(mx, 16, 64));                                       \
        mx = fmaxf(mx, __shfl_xor(mx, 32, 64));                                       \
        float mnew = fmaxf(mi_, mx);                                                  \
        float aa = __expf(mi_ - mnew);                                                \
        mi_ = mnew;                                                                   \
        float rs = 0.f;                                                               \
        _Pragma("unroll") for (int mt = 0; mt < 4; mt++)                              \
            _Pragma("unroll") for (int r = 0; r < 4; r++) {                           \
                float pv = __expf(stt[mt][r] - mnew);                                 \
                stt[mt][r] = pv;                                                      \
                rs += pv;                                                             \
            }                                                                         \
        rs += __shfl_xor(rs, 16, 64);                                                 \
        rs += __shfl_xor(rs, 32, 64);                                                 \
        li_ = li_ * aa + rs;                                                          \
        _Pragma("unroll") for (int mt = 0; mt < 4; mt++)                              \
            _Pragma("unroll") for (int r = 0; r < 4; r++) o_[mt][r] *= aa;            \
        _Pragma("unroll") for (int mt = 0; mt < 4; mt++) {                            \
            bf16x4 pk;                                                                \
            pk[0] = (bf16)stt[mt][0]; pk[1] = (bf16)stt[mt][1];                       \
            pk[2] = (bf16)stt[mt][2]; pk[3] = (bf16)stt[mt][3];                       \
            *(bf16x4*)(psw + l15 * KP2 + mt * 16 + quad * 4) = pk;                    \
        }                                                                             \
        const bf16* vp = vbase + (jtv) * 64;                                          \
        _Pragma("unroll") for (int kc = 0; kc < 2; kc++) {                            \
            bf16x8 pb = *(const bf16x8*)(psw + l15 * KP2 + kc * 32 + quad * 8);       \
            _Pragma("unroll") for (int mt = 0; mt < 4; mt++) {                        \
                bf16x8 va = *(const bf16x8*)(vp + mt * 32768 + kc * 32);              \
                o_[mt] = MFMA16(va, pb, o_[mt]);                                      \
            }                                                                         \
        }                                                                             \
    }

    {   // tile A slots: [s0, min(s1,nttA))
        const int eA = (s1 < nttA) ? s1 : nttA;
        for (int s = s0; s < eA; s++)
            KV_STEP(s, s, (s == nttA - 1), t0A, qfA0, qfA1, miA, liA, oA);
    }
    {   // tile B slots: [max(s0,nttA), s1)
        const int sB = (s0 > nttA) ? s0 : nttA;
        for (int s = sB; s < s1; s++)
            KV_STEP(s, s - nttA, (s == L - 1), t0B, qfB0, qfB1, miB, liB, oB);
    }
#undef KV_STEP

    // ---- hierarchical merge. One round: upper half writes, lower half folds.
#define MERGE_ROUND(act, mi_, li_, o_)                                                \
    {                                                                                 \
        const int half = (act) >> 1;                                                  \
        __syncthreads();                                                              \
        if (w >= half && w < (act)) {                                                 \
            if (lane < 16) { Mb[w - half][lane] = mi_; Lb[w - half][lane] = li_; }    \
            _Pragma("unroll") for (int mt = 0; mt < 4; mt++)                          \
                *(floatx4*)(Ob + ((w - half) * 16 + l15) * OH2 + mt * 16 + quad * 4) = o_[mt]; \
        }                                                                             \
        __syncthreads();                                                              \
        if (w < half) {                                                               \
            float m2 = Mb[w][l15], l2 = Lb[w][l15];                                   \
            float Mn = fmaxf(mi_, m2);                                                \
            float a1 = __expf(mi_ - Mn), a2 = __expf(m2 - Mn);                        \
            mi_ = Mn;                                                                 \
            li_ = li_ * a1 + l2 * a2;                                                 \
            _Pragma("unroll") for (int mt = 0; mt < 4; mt++) {                        \
                floatx4 o2 = *(const floatx4*)(Ob + (w * 16 + l15) * OH2 + mt * 16 + quad * 4); \
                o_[mt] = o_[mt] * a1 + o2 * a2;                                       \
            }                                                                         \
        }                                                                             \
    }

    MERGE_ROUND(16, miA, liA, oA)
    MERGE_ROUND(8,  miA, liA, oA)
    MERGE_ROUND(4,  miA, liA, oA)
    MERGE_ROUND(2,  miA, liA, oA)      // full A now in wave 0
    MERGE_ROUND(16, miB, liB, oB)
    MERGE_ROUND(8,  miB, liB, oB)
    MERGE_ROUND(4,  miB, liB, oB)      // B halves in waves 0,1
#undef MERGE_ROUND

    // asymmetric final: wave 0 hands its B-half to wave 1; outputs in parallel
    __syncthreads();
    if (w == 0) {
        if (lane < 16) { Mb[0][lane] = miB; Lb[0][lane] = liB; }
        #pragma unroll
        for (int mt = 0; mt < 4; mt++)
            *(floatx4*)(Ob + l15 * OH2 + mt * 16 + quad * 4) = oB[mt];
    }
    __syncthreads();
    if (w == 1) {
        float m2 = Mb[0][l15], l2 = Lb[0][l15];
        float Mn = fmaxf(miB, m2);
        float a1 = __expf(miB - Mn), a2 = __expf(m2 - Mn);
        float Lg = liB * a1 + l2 * a2;
        float inv = 1.0f / Lg;
        float* op = out + (size_t)(b * 2048 + t0B + l15) * 64;
        #pragma unroll
        for (int mt = 0; mt < 4; mt++) {
            floatx4 o2 = *(const floatx4*)(Ob + l15 * OH2 + mt * 16 + quad * 4);
            floatx4 ov = (oB[mt] * a1 + o2 * a2) * inv;
            *(floatx4*)(op + mt * 16 + quad * 4) = ov;
        }
    } else if (w == 0) {
        float inv = 1.0f / liA;
        float* op = out + (size_t)(b * 2048 + t0A + l15) * 64;
        #pragma unroll
        for (int mt = 0; mt < 4; mt++) {
            floatx4 ov = oA[mt] * inv;
            *(floatx4*)(op + mt * 16 + quad * 4) = ov;
        }
    }
}

// ---------------------------------------------------------------------------
extern "C" void kernel_launch(void* const* d_in, const int* in_sizes, int n_in,
                              void* d_out, int out_size, void* d_ws, size_t ws_size,
                              hipStream_t stream) {
    const float* x  = (const float*)d_in[0];
    const float* Wq = (const float*)d_in[1];
    const float* Wk = (const float*)d_in[2];
    const float* Wv = (const float*)d_in[3];
    float* out = (float*)d_out;

    char* ws = (char*)d_ws;
    bf16* wTf = (bf16*)ws;                              // 393216 B + slack
    bf16* q   = (bf16*)(ws + 397312);                   // 2 MB
    bf16* k   = (bf16*)(ws + 397312 + 2097152);
    bf16* vT  = (bf16*)(ws + 397312 + 2 * 2097152);     // [b*64+h][2048]

    hipLaunchKernelGGL(prep_w,   dim3(768), dim3(256),  0, stream, Wq, Wk, Wv, wTf);
    hipLaunchKernelGGL(proj_qkv, dim3(512), dim3(256),  0, stream, x, wTf, q, k, vT);
    hipLaunchKernelGGL(flash,    dim3(512), dim3(1024), 0, stream, q, k, vT, out);
}

// Round 9
// 153.102 us; speedup vs baseline: 1.0451x; 1.0451x over previous
//
#include <hip/hip_runtime.h>

typedef __bf16 bf16;
typedef __attribute__((ext_vector_type(8))) __bf16 bf16x8;
typedef __attribute__((ext_vector_type(4))) __bf16 bf16x4;
typedef __attribute__((ext_vector_type(4))) float floatx4;

#define MFMA16(a, b, c) __builtin_amdgcn_mfma_f32_16x16x32_bf16((a), (b), (c), 0, 0, 0)

// ---------------------------------------------------------------------------
// Kernel 0: W [1024][64] fp32 x3 -> wTf, FRAGMENT-MAJOR bf16:
//   wTf[(((mt*32 + kc)*4 + q)*16 + l)*8 + j] = A[m = mt*16+l][k = kc*32+q*8+j]
//   where A[m][c] = W_{m/64}[c][m%64].
// ---------------------------------------------------------------------------
__global__ void prep_w(const float* __restrict__ Wq, const float* __restrict__ Wk,
                       const float* __restrict__ Wv, bf16* __restrict__ wTf) {
    int tid = blockIdx.x * 256 + threadIdx.x;   // [0, 196608)
    int j = tid & 7;
    int l = (tid >> 3) & 15;
    int q = (tid >> 7) & 3;
    int kc = (tid >> 9) & 31;
    int mt = tid >> 14;                          // 0..11
    int mat = mt >> 2;
    int h = ((mt & 3) << 4) + l;
    int c = kc * 32 + q * 8 + j;
    const float* W = (mat == 0) ? Wq : (mat == 1) ? Wk : Wv;
    wTf[tid] = (bf16)W[c * 64 + h];
}

// ---------------------------------------------------------------------------
// Kernel 1: QKV projection. Block = 256 thr (4 waves) = ONE 32-row t-tile.
// Each wave: m-group w (3 m-tiles) x BOTH 16-row t-halves (wTf L2 traffic
// halved vs 16-row blocks). 64 KB LDS x-tile, bf16, XOR-granule swizzle.
// Depth-3 rotating A prefetch. Grid 512 = 2 blocks/CU.
// ---------------------------------------------------------------------------
__global__ __launch_bounds__(256, 4) void proj_qkv(const float* __restrict__ x,
                                                   const bf16* __restrict__ wTf,
                                                   bf16* __restrict__ q,
                                                   bf16* __restrict__ k,
                                                   bf16* __restrict__ vT) {
    __shared__ bf16 xs[32 * 1024];   // 64 KB

    const int tid = threadIdx.x;
    const int lane = tid & 63;
    const int w = tid >> 6;          // wave 0..3 = m-group
    const int l15 = lane & 15;
    const int quad = lane >> 4;
    const int T0 = blockIdx.x * 32;

    // ---- stage: row r = tid>>3, granule set cm = tid&7; slot = g ^ (r&7)
    {
        const int r = tid >> 3;
        const int cm = tid & 7;
        const float* g = x + (size_t)(T0 + r) * 1024 + cm * 8;
        bf16* ld = xs + r * 1024;
        const int sw = r & 7;
        #pragma unroll
        for (int jb = 0; jb < 4; jb++) {
            floatx4 f[8];
            #pragma unroll
            for (int jj = 0; jj < 4; jj++) {
                f[2*jj]   = __builtin_nontemporal_load((const floatx4*)(g + (jb*4+jj) * 64));
                f[2*jj+1] = __builtin_nontemporal_load((const floatx4*)(g + (jb*4+jj) * 64 + 4));
            }
            #pragma unroll
            for (int jj = 0; jj < 4; jj++) {
                int gg = cm + (jb*4+jj) * 8;
                bf16x8 pk;
                pk[0] = (bf16)f[2*jj][0]; pk[1] = (bf16)f[2*jj][1];
                pk[2] = (bf16)f[2*jj][2]; pk[3] = (bf16)f[2*jj][3];
                pk[4] = (bf16)f[2*jj+1][0]; pk[5] = (bf16)f[2*jj+1][1];
                pk[6] = (bf16)f[2*jj+1][2]; pk[7] = (bf16)f[2*jj+1][3];
                *(bf16x8*)(ld + ((gg ^ sw) << 3)) = pk;
            }
        }
    }
    __syncthreads();

    // ---- compute: depth-3 rotating A prefetch, 2 t-tiles per wave
    floatx4 acc[3][2] = {};
    const bf16* aw0 = wTf + (size_t)(w * 3 + 0) * 16384 + lane * 8;
    const bf16* aw1 = wTf + (size_t)(w * 3 + 1) * 16384 + lane * 8;
    const bf16* aw2 = wTf + (size_t)(w * 3 + 2) * 16384 + lane * 8;
    const bf16* xr0 = xs + l15 * 1024;
    const bf16* xr1 = xs + (16 + l15) * 1024;   // same swizzle phase as xr0
    const int swz = l15 & 7;

    bf16x8 A0[3], A1[3], A2[3];
    #pragma unroll
    for (int i = 0; i < 3; i++) {
        A0[i] = *(const bf16x8*)(aw0 + i * 512);
        A1[i] = *(const bf16x8*)(aw1 + i * 512);
        A2[i] = *(const bf16x8*)(aw2 + i * 512);
    }

    #pragma unroll
    for (int kc = 0; kc < 32; kc++) {
        const int idx = kc % 3;
        bf16x8 a0 = A0[idx], a1 = A1[idx], a2 = A2[idx];
        if (kc < 29) {
            A0[idx] = *(const bf16x8*)(aw0 + (kc + 3) * 512);
            A1[idx] = *(const bf16x8*)(aw1 + (kc + 3) * 512);
            A2[idx] = *(const bf16x8*)(aw2 + (kc + 3) * 512);
        }
        const int sl = (((kc * 4 + quad) ^ swz) << 3);
        bf16x8 b0 = *(const bf16x8*)(xr0 + sl);
        bf16x8 b1 = *(const bf16x8*)(xr1 + sl);
        acc[0][0] = MFMA16(a0, b0, acc[0][0]);
        acc[0][1] = MFMA16(a0, b1, acc[0][1]);
        acc[1][0] = MFMA16(a1, b0, acc[1][0]);
        acc[1][1] = MFMA16(a1, b1, acc[1][1]);
        acc[2][0] = MFMA16(a2, b0, acc[2][0]);
        acc[2][1] = MFMA16(a2, b1, acc[2][1]);
    }

    // Epilogue (C-layout; q gets 1/8 scale folded)
    #pragma unroll
    for (int i = 0; i < 3; i++) {
        int mtile = w * 3 + i;
        int mat = mtile >> 2;                          // wave-uniform
        int hbase = ((mtile & 3) << 4) + (quad << 2);
        float sc = (mat == 0) ? 0.125f : 1.0f;
        #pragma unroll
        for (int tt = 0; tt < 2; tt++) {
            int t = T0 + tt * 16 + l15;
            bf16x4 pk;
            pk[0] = (bf16)(acc[i][tt][0] * sc);
            pk[1] = (bf16)(acc[i][tt][1] * sc);
            pk[2] = (bf16)(acc[i][tt][2] * sc);
            pk[3] = (bf16)(acc[i][tt][3] * sc);
            if (mat == 0) {
                *(bf16x4*)(q + (size_t)t * 64 + hbase) = pk;
            } else if (mat == 1) {
                *(bf16x4*)(k + (size_t)t * 64 + hbase) = pk;
            } else {
                int b = t >> 11, tts = t & 2047;
                #pragma unroll
                for (int r = 0; r < 4; r++)
                    vT[(size_t)(b * 64 + hbase + r) * 2048 + tts] = pk[r];
            }
        }
    }
}

// ---------------------------------------------------------------------------
// Kernel 2: causal flash attention, S^T formulation, 512-thr blocks, uniform
// (p, 127-p) Q-tile pair — processed SEQUENTIALLY (phase A: compute+merge+
// store, then phase B) so only one Q-fragment set + one O accumulator is live
// at a time (~70-80 VGPR vs ~96 concurrent / ~116 with K-prefetch). R5/R7/R8
// showed occupancy (wave overlap) beats register-funded prefetching here.
// No K prefetch. Direct identifiers only (R6 lesson: runtime pointers into
// register arrays -> scratch spills).
// ---------------------------------------------------------------------------
#define KP2 72
#define OH2 68

__global__ __launch_bounds__(512, 4) void flash(const bf16* __restrict__ q,
                                                const bf16* __restrict__ k,
                                                const bf16* __restrict__ vT,
                                                float* __restrict__ out) {
    __shared__ char smem[8 * 16 * OH2 * 4];   // union: ps (loop) / Os (merge)
    __shared__ float Ms[8][16], Ls[8][16];
    bf16* psall = (bf16*)smem;
    float* Os = (float*)smem;                 // [8][16][OH2]

    const int b = blockIdx.x & 7;             // batch -> XCD affinity
    const int p = blockIdx.x >> 3;            // 0..63
    const int t0A = p * 16;
    const int t0B = (127 - p) * 16;
    const int nttA = (p >> 2) + 1;            // 1..17
    const int nttB = ((127 - p) >> 2) + 1;    // 16..32

    const int tid = threadIdx.x;
    const int w = tid >> 6;                   // wave 0..7
    const int lane = tid & 63;
    const int l15 = lane & 15;
    const int quad = lane >> 4;

    const bf16* kbase = k + (size_t)(b * 2048 + l15) * 64 + quad * 8;   // + jt*4096 + mt*1024
    const bf16* vbase = vT + (size_t)(b * 64 + l15) * 2048 + quad * 8;  // + mt*32768 + jt*64 + kc*32
    bf16* psw = psall + w * 16 * KP2;

    const bf16* qpA = q + (size_t)(b * 2048 + t0A + l15) * 64 + quad * 8;
    const bf16* qpB = q + (size_t)(b * 2048 + t0B + l15) * 64 + quad * 8;

// One KV step: S^T = K Q^T, per-lane online softmax (row = l15), P via
// wave-private LDS round-trip, O^T += V^T P^T. K loaded inline (no prefetch).
#define KV_STEP(jtv, isdiag, t0v, qf0v, qf1v, mi_, li_, o_)                          \
    {                                                                                 \
        const bf16* kp = kbase + (size_t)(jtv) * 4096;                                \
        floatx4 stt[4];                                                               \
        _Pragma("unroll") for (int mt = 0; mt < 4; mt++) {                            \
            floatx4 z = {};                                                           \
            bf16x8 ka0 = *(const bf16x8*)(kp + mt * 1024);                            \
            bf16x8 ka1 = *(const bf16x8*)(kp + mt * 1024 + 32);                       \
            z = MFMA16(ka0, qf0v, z);                                                 \
            z = MFMA16(ka1, qf1v, z);                                                 \
            stt[mt] = z;                                                              \
        }                                                                             \
        if (isdiag) {                                                                 \
            _Pragma("unroll") for (int mt = 0; mt < 4; mt++)                          \
                _Pragma("unroll") for (int r = 0; r < 4; r++) {                       \
                    int kv = (jtv) * 64 + mt * 16 + quad * 4 + r;                     \
                    if (kv > (t0v) + l15) stt[mt][r] = -1e30f;                        \
                }                                                                     \
        }                                                                             \
        float mx = fmaxf(fmaxf(fmaxf(stt[0][0], stt[0][1]), fmaxf(stt[0][2], stt[0][3])),  \
                         fmaxf(fmaxf(stt[1][0], stt[1][1]), fmaxf(stt[1][2], stt[1][3]))); \
        mx = fmaxf(mx, fmaxf(fmaxf(fmaxf(stt[2][0], stt[2][1]), fmaxf(stt[2][2], stt[2][3])),  \
                             fmaxf(fmaxf(stt[3][0], stt[3][1]), fmaxf(stt[3][2], stt[3][3])))); \
        mx = fmaxf(mx, __shfl_xor(mx, 16, 64));                                       \
        mx = fmaxf(mx, __shfl_xor(mx, 32, 64));                                       \
        float mnew = fmaxf(mi_, mx);                                                  \
        float aa = __expf(mi_ - mnew);                                                \
        mi_ = mnew;                                                                   \
        float rs = 0.f;                                                               \
        _Pragma("unroll") for (int mt = 0; mt < 4; mt++)                              \
            _Pragma("unroll") for (int r = 0; r < 4; r++) {                           \
                float pv = __expf(stt[mt][r] - mnew);                                 \
                stt[mt][r] = pv;                                                      \
                rs += pv;                                                             \
            }                                                                         \
        rs += __shfl_xor(rs, 16, 64);                                                 \
        rs += __shfl_xor(rs, 32, 64);                                                 \
        li_ = li_ * aa + rs;                                                          \
        _Pragma("unroll") for (int mt = 0; mt < 4; mt++)                              \
            _Pragma("unroll") for (int r = 0; r < 4; r++) o_[mt][r] *= aa;            \
        _Pragma("unroll") for (int mt = 0; mt < 4; mt++) {                            \
            bf16x4 pk;                                                                \
            pk[0] = (bf16)stt[mt][0]; pk[1] = (bf16)stt[mt][1];                       \
            pk[2] = (bf16)stt[mt][2]; pk[3] = (bf16)stt[mt][3];                       \
            *(bf16x4*)(psw + l15 * KP2 + mt * 16 + quad * 4) = pk;                    \
        }                                                                             \
        const bf16* vp = vbase + (jtv) * 64;                                          \
        _Pragma("unroll") for (int kc = 0; kc < 2; kc++) {                            \
            bf16x8 pb = *(const bf16x8*)(psw + l15 * KP2 + kc * 32 + quad * 8);       \
            _Pragma("unroll") for (int mt = 0; mt < 4; mt++) {                        \
                bf16x8 va = *(const bf16x8*)(vp + mt * 32768 + kc * 32);              \
                o_[mt] = MFMA16(va, pb, o_[mt]);                                      \
            }                                                                         \
        }                                                                             \
    }

// Flat 8-partial merge + normalized store for one Q tile. Trailing barrier
// protects Os before the next phase's psw writes reuse the region.
#define MERGE_STORE(mi_, li_, o_, t0v)                                                \
    {                                                                                 \
        __syncthreads();                                                              \
        if (lane < 16) { Ms[w][lane] = mi_; Ls[w][lane] = li_; }                      \
        _Pragma("unroll") for (int mt = 0; mt < 4; mt++)                              \
            *(floatx4*)(Os + (w * 16 + l15) * OH2 + mt * 16 + quad * 4) = o_[mt];     \
        __syncthreads();                                                              \
        {                                                                             \
            int qq = tid >> 5;                                                        \
            int h2 = (tid & 31) * 2;                                                  \
            float Mg = -1e30f;                                                        \
            _Pragma("unroll") for (int u = 0; u < 8; u++) Mg = fmaxf(Mg, Ms[u][qq]);  \
            float Lg = 0.f, v0 = 0.f, v1 = 0.f;                                       \
            _Pragma("unroll") for (int u = 0; u < 8; u++) {                           \
                float sw = __expf(Ms[u][qq] - Mg);                                    \
                Lg += sw * Ls[u][qq];                                                 \
                const float* Or = Os + (u * 16 + qq) * OH2 + h2;                      \
                v0 += sw * Or[0];                                                     \
                v1 += sw * Or[1];                                                     \
            }                                                                         \
            float inv = 1.0f / Lg;                                                    \
            float* op = out + (size_t)(b * 2048 + (t0v) + qq) * 64 + h2;              \
            op[0] = v0 * inv;                                                         \
            op[1] = v1 * inv;                                                         \
        }                                                                             \
        __syncthreads();                                                              \
    }

    // ================= Phase A =================
    {
        bf16x8 qfA0 = *(const bf16x8*)qpA;
        bf16x8 qfA1 = *(const bf16x8*)(qpA + 32);
        floatx4 oA[4] = {};
        float miA = -1e30f, liA = 0.f;
        const int a0 = (nttA * w) >> 3;
        const int a1 = (nttA * (w + 1)) >> 3;
        for (int s = a0; s < a1; s++)
            KV_STEP(s, (s == nttA - 1), t0A, qfA0, qfA1, miA, liA, oA);
        MERGE_STORE(miA, liA, oA, t0A)
    }

    // ================= Phase B =================
    {
        bf16x8 qfB0 = *(const bf16x8*)qpB;
        bf16x8 qfB1 = *(const bf16x8*)(qpB + 32);
        floatx4 oB[4] = {};
        float miB = -1e30f, liB = 0.f;
        const int b0 = (nttB * w) >> 3;
        const int b1 = (nttB * (w + 1)) >> 3;
        for (int s = b0; s < b1; s++)
            KV_STEP(s, (s == nttB - 1), t0B, qfB0, qfB1, miB, liB, oB);
        MERGE_STORE(miB, liB, oB, t0B)
    }
#undef KV_STEP
#undef MERGE_STORE
}

// ---------------------------------------------------------------------------
extern "C" void kernel_launch(void* const* d_in, const int* in_sizes, int n_in,
                              void* d_out, int out_size, void* d_ws, size_t ws_size,
                              hipStream_t stream) {
    const float* x  = (const float*)d_in[0];
    const float* Wq = (const float*)d_in[1];
    const float* Wk = (const float*)d_in[2];
    const float* Wv = (const float*)d_in[3];
    float* out = (float*)d_out;

    char* ws = (char*)d_ws;
    bf16* wTf = (bf16*)ws;                              // 393216 B + slack
    bf16* q   = (bf16*)(ws + 397312);                   // 2 MB
    bf16* k   = (bf16*)(ws + 397312 + 2097152);
    bf16* vT  = (bf16*)(ws + 397312 + 2 * 2097152);     // [b*64+h][2048]

    hipLaunchKernelGGL(prep_w,   dim3(768), dim3(256), 0, stream, Wq, Wk, Wv, wTf);
    hipLaunchKernelGGL(proj_qkv, dim3(512), dim3(256), 0, stream, x, wTf, q, k, vT);
    hipLaunchKernelGGL(flash,    dim3(512), dim3(512), 0, stream, q, k, vT, out);
}